// Round 11
// baseline (176.842 us; speedup 1.0000x reference)
//
#include <hip/hip_runtime.h>

#define DSZ   128
#define DMSK  127
#define D3    (DSZ * DSZ * DSZ)

// ETA = 2*gamma*sqrt(KN*MASS), gamma = a/sqrt(a^2+1), a = -ln(0.7)/pi
#define KN_F   500000.0f
#define ETA_F  159.535258f
#define DT_F   1e-4f

// tile: 32 x 4 x 4 cells -> each 128B output line owned by exactly one block
#define TBX   32
#define TBY   4
#define TBZ   4
#define HALO  2
#define RS    37             // padded x-row stride (cells): 36 + 1
#define PS    296            // plane stride = RS * 8
#define SLOTS 2368           // PS * 8
#define NT    512            // threads per block (8 waves)

#define Q512  512.0f
#define IQ512 0.001953125f   // 1/512 (exact)

// ---- tiered offset tables (compile-time, padded pitch) ----------------------
// tier A (33 -> 36 w/ self-pads): r2 <= 4 — where real contacts live.
// tier B (48): r2 in {5,6} — contact only at near-extreme jitter; sq-test+skip.
// exc (44): r2 > 6 — only matters for the rare |pos|^2<4 corner cell whose
//   empty neighbors sit at the origin. Together: exact 125-offset coverage.
struct OffTabs { int a[36]; int b[48]; int e[44]; };
constexpr OffTabs make_tabs() {
    OffTabs t{}; int na = 0, nb = 0, ne = 0;
    for (int dz = -2; dz <= 2; ++dz)
        for (int dy = -2; dy <= 2; ++dy)
            for (int dx = -2; dx <= 2; ++dx) {
                const int r2 = dz*dz + dy*dy + dx*dx;
                const int off = dz * PS + dy * RS + dx;
                if (r2 <= 4)      t.a[na++] = off;
                else if (r2 <= 6) t.b[nb++] = off;
                else              t.e[ne++] = off;
            }
    while (na < 36) t.a[na++] = 0;   // self: exactly zero force
    return t;
}
__constant__ OffTabs g_tabs = make_tabs();

typedef float f4a4 __attribute__((ext_vector_type(4), aligned(4)));

// ---- packing: u16 fixed-point positions (x*512), bf16 velocities ------------
__device__ __forceinline__ unsigned q16(float x) {          // x in [0, 127.5)
    return (unsigned)(int)rintf(x * Q512);
}
__device__ __forceinline__ unsigned bf16_rne(float f) {
    unsigned u = __float_as_uint(f);
    u += 0x7fffu + ((u >> 16) & 1u);
    return u >> 16;
}
__device__ __forceinline__ float unpk_lo(unsigned w) { return __uint_as_float(w << 16); }
__device__ __forceinline__ float unpk_hi(unsigned w) { return __uint_as_float(w & 0xffff0000u); }

// ---- pair force (u16 pos, bf16 vel, single rsq) -----------------------------
// Self-pair exact zero: px == (float)(own_q)*IQ512, fma(-IQ512, own_q, px)==0.
// Empty neighbors: stored all-zero -> reconstruct exactly (0,0,0),v=0.
__device__ __forceinline__ void pair_full(
    const unsigned* __restrict__ lab, const unsigned* __restrict__ lcd,
    const unsigned* __restrict__ lvv, int n,
    float px, float py, float pz, float vx, float vy, float vz,
    float& fx, float& fy, float& fz)
{
    const unsigned ab = lab[n], cd = lcd[n];
    const float ddx = fmaf((float)(ab & 0xffffu), -IQ512, px);
    const float ddy = fmaf((float)(ab >> 16),     -IQ512, py);
    const float ddz = fmaf((float)(cd & 0xffffu), -IQ512, pz);
    const float sq  = fmaf(ddx, ddx, fmaf(ddy, ddy, fmaf(ddz, ddz, 1e-20f)));
    const float rsd = __builtin_amdgcn_rsqf(sq);
    const float dist = sq * rsd;
    const unsigned w = lvv[n];
    const float dvx = vx - __uint_as_float(cd & 0xffff0000u);
    const float dvy = vy - unpk_lo(w);
    const float dvz = vz - unpk_hi(w);
    const float vn = fmaf(dvx, ddx, fmaf(dvy, ddy, dvz * ddz)) * rsd;
    float coef = fmaf(KN_F, dist - 2.0f, ETA_F * vn) * rsd;
    coef = (dist < 2.0f) ? coef : 0.0f;
    fx = fmaf(coef, ddx, fx);
    fy = fmaf(coef, ddy, fy);
    fz = fmaf(coef, ddz, fz);
}

// ---- the kernel -------------------------------------------------------------
// NOTE: no forced min-waves in __launch_bounds__ — R10's (NT,8) clamped VGPR to
// 64 and caused spills; spilled scratch is the only launch-order-dependent
// state, and R10 failed exactly (and only) on graph-replay re-validation.
__global__ __launch_bounds__(NT) void dem_tile(
    const float* __restrict__ X, const float* __restrict__ Y, const float* __restrict__ Z,
    const float* __restrict__ VX, const float* __restrict__ VY, const float* __restrict__ VZ,
    float* __restrict__ out)
{
    __shared__ unsigned lsbuf[3 * SLOTS];   // 28416 B: [pxpy][pz|vx][vy|vz]
    __shared__ unsigned short plist[NT];
    __shared__ int loff[128];               // 36 tierA + 48 tierB + 44 exc
    __shared__ unsigned int pcnt;
    __shared__ int nreloc;
    __shared__ int relocidx[8];
    __shared__ float relocval[8][7];

    unsigned* lab = lsbuf;                  // q16(x) | q16(y)<<16
    unsigned* lcd = lsbuf + SLOTS;          // q16(z) | bf16(vx)<<16
    unsigned* lvv = lsbuf + 2 * SLOTS;      // bf16(vy) | bf16(vz)<<16

    const int tid = threadIdx.x;

    // XCD-aware swizzle: xcd = blockIdx%8 picks a 16-cell-thick z-slab;
    // loc walks x (4) fastest, then y (32), then z-within-slab (4).
    const unsigned raw = blockIdx.x;
    const unsigned xcd = raw & 7, loc = raw >> 3;
    const int bx = (int)((loc & 3) * TBX);
    const int by = (int)(((loc >> 2) & 31) * TBY);
    const int bz = (int)((xcd * 4 + (loc >> 7)) * TBZ);

    if (tid == 0) { pcnt = 0; nreloc = 0; }
    if (tid < 36) loff[tid] = g_tabs.a[tid];
    else if (tid < 84) loff[tid] = g_tabs.b[tid - 36];
    else if (tid < 128) loff[tid] = g_tabs.e[tid - 84];

    // ---- staging: 1536 interior vector units + 192 x-wrap units ---------------
    for (int u = tid; u < 1728; u += NT) {
        if (u < 1536) {
            const int a = u >> 9;          // array 0..2
            const int j = u & 511;
            const int k = j & 7, r = j >> 3;
            const int hz = r >> 3, hy = r & 7;
            const int gz = (bz + hz - HALO) & DMSK;
            const int gy = (by + hy - HALO) & DMSK;
            const int gb = (gz * DSZ + gy) * DSZ + bx + k * 4;
            const float* F0 = (a == 0) ? X : (a == 1) ? Z : VY;
            const float* F1 = (a == 0) ? Y : (a == 1) ? VX : VZ;
            const f4a4 p0 = *(const f4a4*)(F0 + gb);
            const f4a4 p1 = *(const f4a4*)(F1 + gb);
            unsigned* dst = lsbuf + a * SLOTS + hz * PS + hy * RS + HALO + k * 4;
            #pragma unroll
            for (int e = 0; e < 4; ++e)
                dst[e] = (a == 0) ? (q16(p0[e]) | (q16(p1[e]) << 16))
                       : (a == 1) ? (q16(p0[e]) | (bf16_rne(p1[e]) << 16))
                                  : (bf16_rne(p0[e]) | (bf16_rne(p1[e]) << 16));
        } else {
            const int v = u - 1536;        // 192 units: x-wrap halo cells
            const int a = v >> 6;
            const int r = v & 63;
            const int hz = r >> 3, hy = r & 7;
            const int gz = (bz + hz - HALO) & DMSK;
            const int gy = (by + hy - HALO) & DMSK;
            const int rowg = (gz * DSZ + gy) * DSZ;
            const int gxs[4] = { (bx - 2) & DMSK, (bx - 1) & DMSK,
                                 (bx + 32) & DMSK, (bx + 33) & DMSK };
            const int hxs[4] = { 0, 1, 34, 35 };
            const float* F0 = (a == 0) ? X : (a == 1) ? Z : VY;
            const float* F1 = (a == 0) ? Y : (a == 1) ? VX : VZ;
            unsigned* dst = lsbuf + a * SLOTS + hz * PS + hy * RS;
            #pragma unroll
            for (int e = 0; e < 4; ++e) {
                const float f0 = F0[rowg + gxs[e]], f1 = F1[rowg + gxs[e]];
                dst[hxs[e]] = (a == 0) ? (q16(f0) | (q16(f1) << 16))
                            : (a == 1) ? (q16(f0) | (bf16_rne(f1) << 16))
                                       : (bf16_rne(f0) | (bf16_rne(f1) << 16));
            }
        }
    }

    __syncthreads();   // staging done, pcnt/nreloc init visible

    // ---- own cell, compaction -------------------------------------------------
    const int tx = tid & 31, ty = (tid >> 5) & 3, tz = tid >> 7;
    const int cg = ((bz + tz) * DSZ + (by + ty)) * DSZ + (bx + tx);
    const int lcc = (tz + HALO) * PS + (ty + HALO) * RS + (tx + HALO);
    const unsigned oab = lab[lcc];
    // occupied <=> stored x != 0 (occupied cells have x >= 0.8 -> q >= 410)
    const bool occ = ((oab & 0xffffu) != 0u);

    {
        const unsigned long long bmask = __ballot(occ);
        const int lane = tid & 63;
        const unsigned int prefix = (unsigned int)__popcll(bmask & ((1ull << lane) - 1ull));
        unsigned int base = 0;
        if (lane == 0) base = atomicAdd(&pcnt, (unsigned int)__popcll(bmask));
        base = __shfl(base, 0, 64);
        if (occ) plist[base + prefix] = (unsigned short)tid;
    }

    // ---- empty path: all-zero cell -> output all-zero; general reloc kept -----
    float ev[7] = { 0.f, 0.f, 0.f, 0.f, 0.f, 0.f, 0.f };
    if (!occ) {
        const unsigned ocd = lcd[lcc], ow = lvv[lcc];
        const float px = (float)(oab & 0xffffu) * IQ512;
        const float py = (float)(oab >> 16) * IQ512;
        const float pz = (float)(ocd & 0xffffu) * IQ512;
        const float vx = __uint_as_float(ocd & 0xffff0000u);
        const float vy = unpk_lo(ow), vz = unpk_hi(ow);
        const float xn = px + DT_F * vx, yn = py + DT_F * vy, zn = pz + DT_F * vz;
        const int cx0 = (int)rintf(px), cy0 = (int)rintf(py), cz0 = (int)rintf(pz);
        const int cx1 = (int)rintf(xn), cy1 = (int)rintf(yn), cz1 = (int)rintf(zn);
        const int lo = (cx0 && cy0 && cz0) ? ((cz0 * DSZ + cy0) * DSZ + cx0) : D3;
        const int ln = (cx1 && cy1 && cz1) ? ((cz1 * DSZ + cy1) * DSZ + cx1) : D3;
        const bool zeroed = (lo == cg) && (ln != cg);
        const float mk = (ln == cg) ? 1.0f : 0.0f;
        ev[0] = zeroed ? 0.f : xn; ev[1] = zeroed ? 0.f : yn; ev[2] = zeroed ? 0.f : zn;
        ev[3] = zeroed ? 0.f : vx; ev[4] = zeroed ? 0.f : vy; ev[5] = zeroed ? 0.f : vz;
        ev[6] = mk;
        if (lo != cg && lo < D3) {
            int s = atomicAdd(&nreloc, 1);
            if (s < 8) { relocidx[s] = lo; for (int f = 0; f < 7; ++f) relocval[s][f] = 0.f; }
        }
        if (ln != cg && ln < D3) {
            int s = atomicAdd(&nreloc, 1);
            if (s < 8) {
                relocidx[s] = ln;
                relocval[s][0] = xn; relocval[s][1] = yn; relocval[s][2] = zn;
                relocval[s][3] = vx; relocval[s][4] = vy; relocval[s][5] = vz;
                relocval[s][6] = 1.f;
            }
        }
    }

    __syncthreads();   // plist complete

    // ---- force phase: 4 lanes per particle ------------------------------------
    const int n = (int)pcnt;
    const int grp = tid >> 2, sub = tid & 3;
    const int npass = (n + 127) >> 7;
    float fa[4] = { 0.f, 0.f, 0.f, 0.f };
    float fb[4] = { 0.f, 0.f, 0.f, 0.f };
    int fcell[4] = { -1, -1, -1, -1 };

    for (int pp = 0; pp < npass; ++pp) {
        const int i = pp * 128 + grp;
        if (i >= n) break;
        const int p  = plist[i];
        const int px_ = p & 31, py_ = (p >> 5) & 3, pz_ = p >> 7;
        const int lc = (pz_ + HALO) * PS + (py_ + HALO) * RS + (px_ + HALO);
        const int cpg = ((bz + pz_) * DSZ + (by + py_)) * DSZ + (bx + px_);

        const unsigned cab = lab[lc], ccd = lcd[lc], cw = lvv[lc];
        const float px = (float)(cab & 0xffffu) * IQ512;
        const float py = (float)(cab >> 16) * IQ512;
        const float pz = (float)(ccd & 0xffffu) * IQ512;
        const float vx = __uint_as_float(ccd & 0xffff0000u);
        const float vy = unpk_lo(cw), vz = unpk_hi(cw);
        float fx = 0.f, fy = 0.f, fz = 0.f;

        // tier A: real contacts — full compute, no test
        #pragma unroll
        for (int t = 0; t < 9; ++t)
            pair_full(lab, lcd, lvv, lc + loff[t * 4 + sub], px, py, pz, vx, vy, vz, fx, fy, fz);

        // tier B: contact needs near-extreme jitter — sq-test, execz-skip tail
        #pragma unroll
        for (int t = 0; t < 12; ++t) {
            const int nn = lc + loff[36 + t * 4 + sub];
            const unsigned ab = lab[nn], cd = lcd[nn];
            const float ddx = fmaf((float)(ab & 0xffffu), -IQ512, px);
            const float ddy = fmaf((float)(ab >> 16),     -IQ512, py);
            const float ddz = fmaf((float)(cd & 0xffffu), -IQ512, pz);
            const float sq = fmaf(ddx, ddx, fmaf(ddy, ddy, fmaf(ddz, ddz, 1e-20f)));
            if (sq < 4.0f) {
                const float rsd = __builtin_amdgcn_rsqf(sq);
                const float dist = sq * rsd;
                const unsigned w = lvv[nn];
                const float dvx = vx - __uint_as_float(cd & 0xffff0000u);
                const float vn = fmaf(dvx, ddx,
                                   fmaf(vy - unpk_lo(w), ddy, (vz - unpk_hi(w)) * ddz)) * rsd;
                const float coef = fmaf(KN_F, dist - 2.0f, ETA_F * vn) * rsd;
                fx = fmaf(coef, ddx, fx);
                fy = fmaf(coef, ddy, fy);
                fz = fmaf(coef, ddz, fz);
            }
        }

        // empty neighbors sit at the origin: contribute iff |pos|^2 < 4
        // (the (1,1,1)-corner cell) -> run the excluded 44 offsets there.
        const float sqo = fmaf(px, px, fmaf(py, py, pz * pz));
        if (sqo < 4.0f) {
            for (int t = sub; t < 44; t += 4)
                pair_full(lab, lcd, lvv, lc + loff[84 + t], px, py, pz, vx, vy, vz, fx, fy, fz);
        }

        fx += __shfl_xor(fx, 1); fy += __shfl_xor(fy, 1); fz += __shfl_xor(fz, 1);
        fx += __shfl_xor(fx, 2); fy += __shfl_xor(fy, 2); fz += __shfl_xor(fz, 2);

        // boundary forces (mask == 1 here)
        const float bl = (px != 0.0f && px < 1.0f)  ? 1.0f : 0.0f;
        const float br = (px > 126.0f)              ? 1.0f : 0.0f;
        const float bb = (py != 0.0f && py < 1.0f)  ? 1.0f : 0.0f;
        const float bt = (py > 126.0f)              ? 1.0f : 0.0f;
        const float bf = (pz != 0.0f && pz < 1.0f)  ? 1.0f : 0.0f;
        const float bk = (pz > 126.0f)              ? 1.0f : 0.0f;
        const float fxb = KN_F * bl * (1.0f - px) - KN_F * br * (px - 126.0f) - ETA_F * vx * (bl + br);
        const float fyb = KN_F * bb * (1.0f - py) - KN_F * bt * (py - 126.0f) - ETA_F * vy * (bb + bt);
        const float fzb = KN_F * bf * (1.0f - pz) - KN_F * bk * (pz - 126.0f) - ETA_F * vz * (bf + bk);

        const float vxn = vx + DT_F * (-fx + fxb);
        const float vyn = vy + DT_F * (-9.8f - fy + fyb);
        const float vzn = vz + DT_F * (-fz + fzb);
        const float xn = px + DT_F * vxn;
        const float yn = py + DT_F * vyn;
        const float zn = pz + DT_F * vzn;

        const int cx0 = (int)rintf(px), cy0 = (int)rintf(py), cz0 = (int)rintf(pz);
        const int cx1 = (int)rintf(xn), cy1 = (int)rintf(yn), cz1 = (int)rintf(zn);
        const int lo = (cx0 && cy0 && cz0) ? ((cz0 * DSZ + cy0) * DSZ + cx0) : D3;
        const int ln = (cx1 && cy1 && cz1) ? ((cz1 * DSZ + cy1) * DSZ + cx1) : D3;

        const bool zeroed = (lo == cpg) && (ln != cpg);
        const float mk = (ln == cpg) ? 1.0f : (zeroed ? 0.0f : 1.0f);
        const float o0 = zeroed ? 0.f : xn,  o1 = zeroed ? 0.f : yn,  o2 = zeroed ? 0.f : zn;
        const float o3 = zeroed ? 0.f : vxn, o4 = zeroed ? 0.f : vyn, o5 = zeroed ? 0.f : vzn;

        fcell[pp] = p;
        fa[pp] = (sub == 0) ? o0 : (sub == 1) ? o1 : (sub == 2) ? o2 : o3;
        fb[pp] = (sub == 0) ? o4 : (sub == 1) ? o5 : mk;

        if (sub == 0) {   // rare relocation: queue direct fixups
            if (lo != cpg && lo < D3) {
                int s = atomicAdd(&nreloc, 1);
                if (s < 8) { relocidx[s] = lo; for (int f = 0; f < 7; ++f) relocval[s][f] = 0.f; }
            }
            if (ln != cpg && ln < D3) {
                int s = atomicAdd(&nreloc, 1);
                if (s < 8) {
                    relocidx[s] = ln;
                    relocval[s][0] = xn;  relocval[s][1] = yn;  relocval[s][2] = zn;
                    relocval[s][3] = vxn; relocval[s][4] = vyn; relocval[s][5] = vzn;
                    relocval[s][6] = 1.f;
                }
            }
        }
    }

    __syncthreads();   // all lsbuf force reads complete -> safe to overlay res

    // ---- result staging (res overlays lsbuf) ----------------------------------
    float* res = (float*)lsbuf;            // 7*512 floats = 14336 B <= 28416 B
    if (!occ) {
        #pragma unroll
        for (int f = 0; f < 7; ++f) res[f * 512 + tid] = ev[f];
    }
    #pragma unroll
    for (int pp = 0; pp < 4; ++pp) {
        if (fcell[pp] >= 0) {
            res[sub * 512 + fcell[pp]] = fa[pp];
            if (sub < 3) res[(sub + 4) * 512 + fcell[pp]] = fb[pp];
        }
    }

    __syncthreads();   // res complete

    // ---- fully-coalesced writeback: 7 fields x 128 dwordx4 --------------------
    for (int u = tid; u < 896; u += NT) {
        const int f = u >> 7, j = u & 127;
        const int cell = 4 * j;
        const int wtx = cell & 31, wty = (cell >> 5) & 3, wtz = cell >> 7;
        const float4 v = *(const float4*)(res + f * 512 + cell);
        *(float4*)(out + f * D3 + ((bz + wtz) * DSZ + (by + wty)) * DSZ + bx + wtx) = v;
    }

    // ---- rare relocation fixups (never triggers at DT=1e-4) -------------------
    __syncthreads();
    const int nr = nreloc < 8 ? nreloc : 8;
    if (tid < nr) {
        const int idx = relocidx[tid];
        #pragma unroll
        for (int f = 0; f < 7; ++f) out[idx + f * D3] = relocval[tid][f];
    }
}

extern "C" void kernel_launch(void* const* d_in, const int* in_sizes, int n_in,
                              void* d_out, int out_size, void* d_ws, size_t ws_size,
                              hipStream_t stream)
{
    const float* X  = (const float*)d_in[0];
    const float* Y  = (const float*)d_in[1];
    const float* Z  = (const float*)d_in[2];
    const float* VX = (const float*)d_in[3];
    const float* VY = (const float*)d_in[4];
    const float* VZ = (const float*)d_in[5];
    float* out = (float*)d_out;

    dem_tile<<<(D3 / (TBX * TBY * TBZ)), NT, 0, stream>>>(X, Y, Z, VX, VY, VZ, out);
}